// Round 1
// baseline (18268.823 us; speedup 1.0000x reference)
//
#include <hip/hip_runtime.h>

#define SLEN 64
#define BSZ  64
#define TSL  48
#define VDIM 32000
#define NCOL 32064   // VDIM + SLEN

__device__ __forceinline__ float fsig(float x){
    return 1.0f/(1.0f + __expf(-x));
}
__device__ __forceinline__ float ftanh(float x){
    float e = __expf(2.0f*x);
    return 1.0f - 2.0f/(e + 1.0f);
}

// ---------------------------------------------------------------------------
// Tiled 64x64 fp32 GEMM:  C = A @ B^T (+bias) (opt tanh). A:(M,K) B:(N,K) row-major.
// grid = (N/64, M/64, nz); z selects pointer set (for fusing two independent GEMMs).
// ---------------------------------------------------------------------------
__global__ __launch_bounds__(256) void gemm64(
    const float* A0, const float* B0, const float* bias0, float* C0, int act0,
    const float* A1, const float* B1, const float* bias1, float* C1, int act1,
    int M, int N, int K, int ldc)
{
    const float* A  = blockIdx.z ? A1 : A0;
    const float* B  = blockIdx.z ? B1 : B0;
    const float* bp = blockIdx.z ? bias1 : bias0;
    float*       C  = blockIdx.z ? C1 : C0;
    const int act   = blockIdx.z ? act1 : act0;

    __shared__ float As[32*68];
    __shared__ float Bs[32*68];

    const int n0 = blockIdx.x * 64;
    const int m0 = blockIdx.y * 64;
    const int t  = threadIdx.x;
    const int lrow = t >> 3;       // 0..31
    const int lc4  = t & 7;        // 0..7
    const int tm = (t >> 4) << 2;  // 0..60
    const int tn = (t & 15) << 2;  // 0..60

    float acc[4][4] = {};

    for (int k0 = 0; k0 < K; k0 += 32) {
        float4 a0 = *reinterpret_cast<const float4*>(A + (size_t)(m0+lrow   )*K + k0 + lc4*4);
        float4 a1 = *reinterpret_cast<const float4*>(A + (size_t)(m0+lrow+32)*K + k0 + lc4*4);
        float4 b0 = *reinterpret_cast<const float4*>(B + (size_t)(n0+lrow   )*K + k0 + lc4*4);
        float4 b1 = *reinterpret_cast<const float4*>(B + (size_t)(n0+lrow+32)*K + k0 + lc4*4);
        __syncthreads();
        const int kb = lc4*4;
        As[(kb+0)*68 + lrow]    = a0.x; As[(kb+1)*68 + lrow]    = a0.y;
        As[(kb+2)*68 + lrow]    = a0.z; As[(kb+3)*68 + lrow]    = a0.w;
        As[(kb+0)*68 + lrow+32] = a1.x; As[(kb+1)*68 + lrow+32] = a1.y;
        As[(kb+2)*68 + lrow+32] = a1.z; As[(kb+3)*68 + lrow+32] = a1.w;
        Bs[(kb+0)*68 + lrow]    = b0.x; Bs[(kb+1)*68 + lrow]    = b0.y;
        Bs[(kb+2)*68 + lrow]    = b0.z; Bs[(kb+3)*68 + lrow]    = b0.w;
        Bs[(kb+0)*68 + lrow+32] = b1.x; Bs[(kb+1)*68 + lrow+32] = b1.y;
        Bs[(kb+2)*68 + lrow+32] = b1.z; Bs[(kb+3)*68 + lrow+32] = b1.w;
        __syncthreads();
        #pragma unroll
        for (int kk = 0; kk < 32; ++kk) {
            float4 av = *reinterpret_cast<const float4*>(As + kk*68 + tm);
            float4 bv = *reinterpret_cast<const float4*>(Bs + kk*68 + tn);
            acc[0][0] += av.x*bv.x; acc[0][1] += av.x*bv.y; acc[0][2] += av.x*bv.z; acc[0][3] += av.x*bv.w;
            acc[1][0] += av.y*bv.x; acc[1][1] += av.y*bv.y; acc[1][2] += av.y*bv.z; acc[1][3] += av.y*bv.w;
            acc[2][0] += av.z*bv.x; acc[2][1] += av.z*bv.y; acc[2][2] += av.z*bv.z; acc[2][3] += av.z*bv.w;
            acc[3][0] += av.w*bv.x; acc[3][1] += av.w*bv.y; acc[3][2] += av.w*bv.z; acc[3][3] += av.w*bv.w;
        }
    }

    #pragma unroll
    for (int i = 0; i < 4; ++i) {
        float r0 = acc[i][0], r1 = acc[i][1], r2 = acc[i][2], r3 = acc[i][3];
        if (bp) { r0 += bp[n0+tn+0]; r1 += bp[n0+tn+1]; r2 += bp[n0+tn+2]; r3 += bp[n0+tn+3]; }
        if (act) { r0 = ftanh(r0); r1 = ftanh(r1); r2 = ftanh(r2); r3 = ftanh(r3); }
        float4 v = make_float4(r0, r1, r2, r3);
        *reinterpret_cast<float4*>(C + (size_t)(m0+tm+i)*ldc + (n0+tn)) = v;
    }
}

// ---------------------------------------------------------------------------
// Skinny GEMM for M=64: tile 16 rows x 64 cols. grid = (N/64, 4, nz).
// C = A @ B^T + bias.  A:(64,K)  B:(N,K).
// ---------------------------------------------------------------------------
__global__ __launch_bounds__(256) void gemm_skinny(
    const float* A0, const float* B0, const float* bias0, float* C0,
    const float* A1, const float* B1, const float* bias1, float* C1,
    int N, int K, int ldc)
{
    const float* A  = blockIdx.z ? A1 : A0;
    const float* B  = blockIdx.z ? B1 : B0;
    const float* bp = blockIdx.z ? bias1 : bias0;
    float*       C  = blockIdx.z ? C1 : C0;

    __shared__ float As[16*64];
    const int n0 = blockIdx.x * 64;
    const int m0 = blockIdx.y * 16;
    const int t  = threadIdx.x;
    const int n  = t & 63;
    const int mb = t >> 6;   // 0..3

    float acc[4] = {};

    for (int k0 = 0; k0 < K; k0 += 64) {
        __syncthreads();
        const int row = t >> 4, c4 = t & 15;
        *reinterpret_cast<float4*>(As + row*64 + c4*4) =
            *reinterpret_cast<const float4*>(A + (size_t)(m0+row)*K + k0 + c4*4);
        __syncthreads();
        const float* Bp = B + (size_t)(n0+n)*K + k0;
        #pragma unroll
        for (int q = 0; q < 16; ++q) {
            float4 bv = *reinterpret_cast<const float4*>(Bp + q*4);
            #pragma unroll
            for (int mm = 0; mm < 4; ++mm) {
                float4 av = *reinterpret_cast<const float4*>(As + (mb + 4*mm)*64 + q*4);
                acc[mm] += av.x*bv.x + av.y*bv.y + av.z*bv.z + av.w*bv.w;
            }
        }
    }
    const float bz = bp ? bp[n0+n] : 0.0f;
    #pragma unroll
    for (int mm = 0; mm < 4; ++mm)
        C[(size_t)(m0 + mb + 4*mm)*ldc + n0 + n] = acc[mm] + bz;
}

// ---------------------------------------------------------------------------
// Encoder embedding gather: x[s*64+b][0..512) = emb_enc[inp[s*64+b]]
// ---------------------------------------------------------------------------
__global__ __launch_bounds__(256) void embed_k(const int* inp, const float* emb, float* x)
{
    int i = blockIdx.x*256 + threadIdx.x;       // 4096*128 float4s
    if (i >= 4096*128) return;
    int row = i >> 7, c4 = i & 127;
    int tok = inp[row];
    *reinterpret_cast<float4*>(x + (size_t)row*512 + c4*4) =
        *reinterpret_cast<const float4*>(emb + (size_t)tok*512 + c4*4);
}

__global__ __launch_bounds__(256) void transpose_k(const float* W1, float* W1T)
{
    int i = blockIdx.x*256 + threadIdx.x;       // 768*512
    if (i >= 512*768) return;
    int n = i / 512, k = i % 512;
    W1T[i] = W1[(size_t)k*768 + n];
}

__global__ __launch_bounds__(256) void zero_k(float* p, int nelem)
{
    int i = blockIdx.x*256 + threadIdx.x;
    if (i < nelem) p[i] = 0.0f;
}

// ---------------------------------------------------------------------------
// One encoder GRU timestep, both directions. grid (64 b, 2 dir), 256 threads.
// gi buffers already hold x@Wih^T+bih for all timesteps.
// ---------------------------------------------------------------------------
__global__ __launch_bounds__(256) void enc_step_k(
    const float* giF, const float* giB,
    const float* Whh,   // layer base: [2][768][256]
    const float* bhh,   // layer base: [2][768]
    float* hS,          // layer base: [2][64][256]
    float* yout,        // [4096][512]
    float* hfin,        // layer base: [64][512]
    int step)
{
    const int b = blockIdx.x, d = blockIdx.y, t = threadIdx.x;
    const int s = d ? (63 - step) : step;
    const float* gi = (d ? giB : giF) + (size_t)(s*64 + b)*768;
    const float* W  = Whh + (size_t)d*768*256;
    const float* bh = bhh + d*768;
    float* h = hS + (size_t)(d*64 + b)*256;

    __shared__ float hs[256];
    hs[t] = h[t];
    __syncthreads();

    float ar = 0.f, az = 0.f, an = 0.f;
    #pragma unroll 8
    for (int q = 0; q < 64; ++q) {
        float4 hv = *reinterpret_cast<const float4*>(hs + q*4);
        float4 wr = *reinterpret_cast<const float4*>(W + (size_t)(t      )*256 + q*4);
        float4 wz = *reinterpret_cast<const float4*>(W + (size_t)(t + 256)*256 + q*4);
        float4 wn = *reinterpret_cast<const float4*>(W + (size_t)(t + 512)*256 + q*4);
        ar += hv.x*wr.x + hv.y*wr.y + hv.z*wr.z + hv.w*wr.w;
        az += hv.x*wz.x + hv.y*wz.y + hv.z*wz.z + hv.w*wz.w;
        an += hv.x*wn.x + hv.y*wn.y + hv.z*wn.z + hv.w*wn.w;
    }
    ar += bh[t]; az += bh[t+256]; an += bh[t+512];

    float r = fsig(gi[t]       + ar);
    float z = fsig(gi[t + 256] + az);
    float n = ftanh(gi[t + 512] + r*an);
    float hn2 = (1.0f - z)*n + z*hs[t];

    h[t] = hn2;
    yout[(size_t)(s*64 + b)*512 + d*256 + t] = hn2;
    if (step == 63) hfin[(size_t)b*512 + d*256 + t] = hn2;
}

// ---------------------------------------------------------------------------
// Attention scores: scores[b][s] = sum_e tanh(w1e[s,b,e] + w2h[b,e]) * Vp[e]
// grid (64 b, 4 s-chunks), 256 threads (4 waves x 4 s each).
// ---------------------------------------------------------------------------
__global__ __launch_bounds__(256) void att1_k(
    const float* w1e, const float* w2h, const float* Vp, float* scores)
{
    const int b = blockIdx.x, sc = blockIdx.y, t = threadIdx.x;
    __shared__ float w2s[768];
    __shared__ float vps[768];
    for (int i = t; i < 768; i += 256) { w2s[i] = w2h[(size_t)b*768 + i]; vps[i] = Vp[i]; }
    __syncthreads();
    const int wave = t >> 6, lane = t & 63;
    #pragma unroll
    for (int ss = 0; ss < 4; ++ss) {
        const int s = sc*16 + wave*4 + ss;
        const float* wrow = w1e + (size_t)(s*64 + b)*768;
        float acc = 0.f;
        #pragma unroll
        for (int q = 0; q < 12; ++q) {
            int e = lane + q*64;
            acc += ftanh(wrow[e] + w2s[e]) * vps[e];
        }
        for (int off = 32; off; off >>= 1) acc += __shfl_down(acc, off);
        if (lane == 0) scores[b*64 + s] = acc;
    }
}

// ---------------------------------------------------------------------------
// Attention softmax over s + context Xa + decoder-input embedding gather.
// Builds wgt_in[b][0..768)=emb_dec[tok], [768..1280)=Xa.  grid 64, 256 thr.
// ---------------------------------------------------------------------------
__global__ __launch_bounds__(256) void att2_k(
    const float* scores, const float* enc_out, const float* emb_dec,
    const int* y, int step, float* wgt_in)
{
    const int b = blockIdx.x, t = threadIdx.x;
    __shared__ float a[64];
    if (t < 64) {
        float v = scores[b*64 + t];
        float m = v;
        for (int off = 32; off; off >>= 1) m = fmaxf(m, __shfl_xor(m, off));
        float e = __expf(v - m);
        float ssum = e;
        for (int off = 32; off; off >>= 1) ssum += __shfl_xor(ssum, off);
        a[t] = e / ssum;
    }
    __syncthreads();
    for (int e = t; e < 512; e += 256) {
        float acc = 0.f;
        #pragma unroll 8
        for (int s = 0; s < 64; ++s)
            acc += a[s] * enc_out[(size_t)(s*64 + b)*512 + e];
        wgt_in[(size_t)b*1280 + 768 + e] = acc;
    }
    const int tok = (step == 0) ? 0 : y[(step-1)*64 + b];
    for (int e = t; e < 768; e += 256)
        wgt_in[(size_t)b*1280 + e] = emb_dec[(size_t)tok*768 + e];
}

// ---------------------------------------------------------------------------
// Decoder GRU gate combine (hidden dim 768). grid 192, 256 threads.
// ---------------------------------------------------------------------------
__global__ __launch_bounds__(256) void gru_gate_k(
    const float* gi, const float* gh, const float* hold, float* hnew)
{
    int idx = blockIdx.x*256 + threadIdx.x;
    if (idx >= 64*768) return;
    int b = idx / 768, j = idx % 768;
    const float* gib = gi + (size_t)b*2304;
    const float* ghb = gh + (size_t)b*2304;
    float r = fsig(gib[j]        + ghb[j]);
    float z = fsig(gib[j + 768]  + ghb[j + 768]);
    float n = ftanh(gib[j + 1536] + r*ghb[j + 1536]);
    hnew[idx] = (1.0f - z)*n + z*hold[idx];
}

// ---------------------------------------------------------------------------
// Copy scores: out[b][VDIM+s] = tanh(dot(sc_base[s,b,:], h1[b,:])). grid 64.
// ---------------------------------------------------------------------------
__global__ __launch_bounds__(256) void scorec_k(
    const float* sc_base, const float* h1, float* outstep)
{
    const int b = blockIdx.x, t = threadIdx.x;
    __shared__ float hsh[768];
    for (int i = t; i < 768; i += 256) hsh[i] = h1[(size_t)b*768 + i];
    __syncthreads();
    const int wave = t >> 6, lane = t & 63;
    for (int ss = 0; ss < 16; ++ss) {
        const int s = wave*16 + ss;
        const float* sp = sc_base + (size_t)(s*64 + b)*768;
        float acc = 0.f;
        #pragma unroll
        for (int q = 0; q < 12; ++q) { int e = lane + q*64; acc += sp[e]*hsh[e]; }
        for (int off = 32; off; off >>= 1) acc += __shfl_down(acc, off);
        if (lane == 0) outstep[(size_t)b*NCOL + VDIM + s] = ftanh(acc);
    }
}

// ---------------------------------------------------------------------------
// Row softmax over 32064 logits (in place) + copy-scatter. grid 64 x 1024.
// ---------------------------------------------------------------------------
__global__ __launch_bounds__(1024) void smax_k(float* outstep, const int* y)
{
    const int b = blockIdx.x, t = threadIdx.x;
    float* row = outstep + (size_t)b*NCOL;
    __shared__ float redm[16];
    __shared__ float reds[16];
    __shared__ float pc[64];

    float v[32];
    float m = -1e30f;
    #pragma unroll
    for (int i = 0; i < 32; ++i) {
        int idx = t + i*1024;
        v[i] = (idx < NCOL) ? row[idx] : -1e30f;
        m = fmaxf(m, v[i]);
    }
    for (int off = 32; off; off >>= 1) m = fmaxf(m, __shfl_xor(m, off));
    if ((t & 63) == 0) redm[t >> 6] = m;
    __syncthreads();
    float bm = -1e30f;
    #pragma unroll
    for (int i = 0; i < 16; ++i) bm = fmaxf(bm, redm[i]);

    float s = 0.f;
    #pragma unroll
    for (int i = 0; i < 32; ++i) {
        int idx = t + i*1024;
        if (idx < NCOL) { v[i] = __expf(v[i] - bm); s += v[i]; }
    }
    for (int off = 32; off; off >>= 1) s += __shfl_xor(s, off);
    if ((t & 63) == 0) reds[t >> 6] = s;
    __syncthreads();
    float bs_ = 0.f;
    #pragma unroll
    for (int i = 0; i < 16; ++i) bs_ += reds[i];
    const float inv = 1.0f / bs_;

    #pragma unroll
    for (int i = 0; i < 32; ++i) {
        int idx = t + i*1024;
        if (idx < VDIM)       row[idx] = v[i] * inv;
        else if (idx < NCOL) { pc[idx - VDIM] = v[i] * inv; row[idx] = 0.0f; }
    }
    __syncthreads();
    if (t < 64) {
        int tok = y[t*64 + b];
        atomicAdd(&row[tok], pc[t]);
    }
}

// ---------------------------------------------------------------------------
extern "C" void kernel_launch(void* const* d_in, const int* in_sizes, int n_in,
                              void* d_out, int out_size, void* d_ws, size_t ws_size,
                              hipStream_t stream)
{
    (void)in_sizes; (void)n_in; (void)out_size; (void)ws_size;
    const int*   inp       = (const int*)  d_in[0];
    const int*   y         = (const int*)  d_in[1];
    const float* emb_enc   = (const float*)d_in[2];
    const float* enc_Wih   = (const float*)d_in[3];
    const float* enc_Whh   = (const float*)d_in[4];
    const float* enc_bih   = (const float*)d_in[5];
    const float* enc_bhh   = (const float*)d_in[6];
    const float* out_enc_W = (const float*)d_in[7];
    const float* emb_dec   = (const float*)d_in[8];
    const float* dec_Wih   = (const float*)d_in[9];
    const float* dec_Whh   = (const float*)d_in[10];
    const float* dec_bih   = (const float*)d_in[11];
    const float* dec_bhh   = (const float*)d_in[12];
    const float* out_b     = (const float*)d_in[13];
    const float* W1        = (const float*)d_in[14];
    const float* l2_W      = (const float*)d_in[15];
    const float* l2_b      = (const float*)d_in[16];
    const float* l3_W      = (const float*)d_in[17];
    const float* l3_b      = (const float*)d_in[18];
    const float* Vp        = (const float*)d_in[19];
    float* out = (float*)d_out;
    float* ws  = (float*)d_ws;

    size_t off = 0;
    auto alloc = [&](size_t n) { float* p = ws + off; off += (n + 63) & ~(size_t)63; return p; };
    float* x0     = alloc(4096*512);
    float* x1     = alloc(4096*512);
    float* x2     = alloc(4096*512);   // enc_out
    float* giF    = alloc(4096*768);
    float* giB    = alloc(4096*768);
    float* w1e    = alloc(4096*768);
    float* scb    = alloc(4096*768);
    float* W1T    = alloc(768*512);
    float* hS     = alloc(2*2*64*256);
    float* hfin   = alloc(128*512);
    float* hdecA  = alloc(128*768);
    float* hdecB  = alloc(128*768);
    float* w2h    = alloc(64*768);
    float* scores = alloc(64*64);
    float* wgt_in = alloc(64*1280);
    float* wgt    = alloc(64*768);
    float* gibuf  = alloc(64*2304);
    float* ghbuf  = alloc(64*2304);

    // ---- encoder ----
    embed_k<<<2048, 256, 0, stream>>>(inp, emb_enc, x0);
    transpose_k<<<(512*768 + 255)/256, 256, 0, stream>>>(W1, W1T);
    zero_k<<<(2*2*64*256 + 255)/256, 256, 0, stream>>>(hS, 2*2*64*256);

    for (int l = 0; l < 2; ++l) {
        const float* xin  = l ? x1 : x0;
        float*       xout = l ? x2 : x1;
        const float* Wih = enc_Wih + (size_t)l*2*768*512;
        const float* Whh = enc_Whh + (size_t)l*2*768*256;
        const float* bih = enc_bih + (size_t)l*2*768;
        const float* bhh = enc_bhh + (size_t)l*2*768;
        gemm64<<<dim3(12, 64, 2), 256, 0, stream>>>(
            xin, Wih,           bih,       giF, 0,
            xin, Wih + 768*512, bih + 768, giB, 0,
            4096, 768, 512, 768);
        for (int st = 0; st < 64; ++st)
            enc_step_k<<<dim3(64, 2), 256, 0, stream>>>(
                giF, giB, Whh, bhh, hS + (size_t)l*2*64*256, xout,
                hfin + (size_t)l*64*512, st);
    }

    // decoder initial hidden: (2*64,512) @ out_enc_W^T -> (128,768)
    gemm64<<<dim3(12, 2, 1), 256, 0, stream>>>(
        hfin, out_enc_W, nullptr, hdecA, 0,
        hfin, out_enc_W, nullptr, hdecA, 0,
        128, 768, 512, 768);

    // w1e = enc_out @ W1 (via pre-transposed W1T) ; sc_base = tanh(enc_out @ out_enc_W^T)
    gemm64<<<dim3(12, 64, 2), 256, 0, stream>>>(
        x2, W1T,       nullptr, w1e, 0,
        x2, out_enc_W, nullptr, scb, 1,
        4096, 768, 512, 768);

    // ---- decoder ----
    for (int st = 0; st < TSL; ++st) {
        float* hcur  = (st & 1) ? hdecB : hdecA;
        float* hnext = (st & 1) ? hdecA : hdecB;
        float* orow  = out + (size_t)st*BSZ*NCOL;

        gemm_skinny<<<dim3(12, 4, 1), 256, 0, stream>>>(
            hcur + 64*768, l2_W, l2_b, w2h,
            hcur + 64*768, l2_W, l2_b, w2h,
            768, 768, 768);
        att1_k<<<dim3(64, 4), 256, 0, stream>>>(w1e, w2h, Vp, scores);
        att2_k<<<64, 256, 0, stream>>>(scores, x2, emb_dec, y, st, wgt_in);
        gemm_skinny<<<dim3(12, 4, 1), 256, 0, stream>>>(
            wgt_in, l3_W, l3_b, wgt,
            wgt_in, l3_W, l3_b, wgt,
            768, 1280, 768);

        // layer 0: gi = wgt @ Wih0^T ; gh = h0 @ Whh0^T   (fused via z)
        gemm_skinny<<<dim3(36, 4, 2), 256, 0, stream>>>(
            wgt,  dec_Wih, dec_bih, gibuf,
            hcur, dec_Whh, dec_bhh, ghbuf,
            2304, 768, 2304);
        gru_gate_k<<<192, 256, 0, stream>>>(gibuf, ghbuf, hcur, hnext);

        // layer 1
        gemm_skinny<<<dim3(36, 4, 2), 256, 0, stream>>>(
            hnext,          dec_Wih + (size_t)2304*768, dec_bih + 2304, gibuf,
            hcur + 64*768,  dec_Whh + (size_t)2304*768, dec_bhh + 2304, ghbuf,
            2304, 768, 2304);
        gru_gate_k<<<192, 256, 0, stream>>>(gibuf, ghbuf, hcur + 64*768, hnext + 64*768);

        // vocab logits into output row (cols 0..32000)
        gemm64<<<dim3(500, 1, 1), 256, 0, stream>>>(
            hnext + 64*768, emb_dec, out_b, orow, 0,
            hnext + 64*768, emb_dec, out_b, orow, 0,
            64, 32000, 768, NCOL);
        scorec_k<<<64, 256, 0, stream>>>(scb, hnext + 64*768, orow);
        smax_k<<<64, 1024, 0, stream>>>(orow, y);
    }
}